// Round 12
// baseline (309.175 us; speedup 1.0000x reference)
//
#include <hip/hip_runtime.h>
#include <hip/hip_bf16.h>
#include <math.h>

// GAT forward: N=100000, E=1.6M (row sorted = dest), F_IN=128, F_OUT=32,
// HEADS=8, ALPHA=0.2. Output [N, 256] f32.
//
// Round 12 (single change: scatter re-lane, grouped weights):
//  - gat_scatter: lane l = (dp = l>>3, h = l&7). Pass A computes w for
//    (edge 8g+dp, head h) -> ONE exp per (edge,head), 8x fewer than R11;
//    sm reduced once at the end over the dp axis. Pass B: w via one
//    shfl(w, 8i+h) per edge, same uint2-decode/4-fma body. Unified window
//    loop handles any deg (no separate slow path).
//  - prep0 / aproj_conv / feat_gemm_mfma byte-identical to R11 (passed).

#define F_IN   128
#define F_ALL  256   // HEADS * F_OUT
#define HEADS  8
#define F_OUT  32
#define ALPHA  0.2f

using f32x4  = __attribute__((ext_vector_type(4))) float;
using bf16x8 = __attribute__((ext_vector_type(8))) short;

static __device__ __forceinline__ unsigned short f32_to_bf16(float f) {
  union { float f; unsigned u; } v; v.f = f;
  unsigned r = v.u + 0x7FFF + ((v.u >> 16) & 1);   // RNE
  return (unsigned short)(r >> 16);
}
static __device__ __forceinline__ unsigned cvt_pk_bf16(float lo, float hi) {
  unsigned r;
  asm("v_cvt_pk_bf16_f32 %0, %1, %2" : "=v"(r) : "v"(lo), "v"(hi));
  return r;
}
static __device__ __forceinline__ float bf16_lo(unsigned d) {
  return __uint_as_float(d << 16);
}
static __device__ __forceinline__ float bf16_hi(unsigned d) {
  return __uint_as_float(d & 0xffff0000u);
}

// ---- 0) prep0: ws/wn = W@att (f32), Wt[256][128] bf16, CSR ptr ----
__global__ __launch_bounds__(256) void prep0(const float* __restrict__ kern,
                                             const float* __restrict__ att_s,
                                             const float* __restrict__ att_n,
                                             const int* __restrict__ row,
                                             unsigned short* __restrict__ Wt,
                                             float* __restrict__ ws,
                                             float* __restrict__ wn,
                                             int* __restrict__ ptr,
                                             int N, int E) {
  int id = blockIdx.x * 256 + threadIdx.x;
  if (id < 2 * HEADS * F_IN) {      // ws[h][k], wn[h][k] (f32, exact)
    int which = id >> 10;
    int hk = id & 1023;
    int h = hk >> 7, k = hk & 127;
    const float* att = which ? att_n : att_s;
    float s = 0.f;
#pragma unroll
    for (int f = 0; f < F_OUT; ++f)
      s += kern[(size_t)h * (F_IN * F_OUT) + k * F_OUT + f] * att[h * F_OUT + f];
    (which ? wn : ws)[hk] = s;
  } else if (id < 4096) {           // Wt[c][k] = kern[c>>5][k][c&31], 16/thread
    int base = (id - 2048) * 16;
#pragma unroll
    for (int i = base; i < base + 16; ++i) {
      int c = i >> 7, k = i & 127;
      Wt[i] = f32_to_bf16(kern[(size_t)(c >> 5) * (F_IN * F_OUT) + k * F_OUT + (c & 31)]);
    }
  }
  if (id <= N) {                    // CSR offsets via binary search
    int lo = 0, hi = E;
    while (lo < hi) {
      int mid = (lo + hi) >> 1;
      if (row[mid] < id) lo = mid + 1; else hi = mid;
    }
    ptr[id] = lo;
  }
}

// ---- 1) aproj_conv: a_s/a_n (exact f32) + x->bf16, x read once ----
// wave per node: lane l = q*16+o; q = k-quarter (32 floats), o = output 0..15
__global__ __launch_bounds__(256) void aproj_conv(const float* __restrict__ x,
                                                  const float* __restrict__ ws,
                                                  const float* __restrict__ wn,
                                                  unsigned short* __restrict__ xb,
                                                  float* __restrict__ a_s,
                                                  float* __restrict__ a_n, int N) {
  const int t = threadIdx.x;
  const int l = t & 63;
  const int o = l & 15, q = l >> 4;
  const int wid = (blockIdx.x * 256 + t) >> 6;
  const int nw  = (gridDim.x * 256) >> 6;

  const float* wrow = (o < 8 ? ws + o * F_IN : wn + (o - 8) * F_IN) + q * 32;
  float4 wv[8];
#pragma unroll
  for (int i = 0; i < 8; i++) wv[i] = reinterpret_cast<const float4*>(wrow)[i];

  for (int n = wid; n < N; n += nw) {
    const float4* xr = reinterpret_cast<const float4*>(x + (size_t)n * F_IN + q * 32);
    float acc = 0.f;
#pragma unroll
    for (int i = 0; i < 8; i++) {
      float4 xv = xr[i];
      acc += xv.x * wv[i].x + xv.y * wv[i].y + xv.z * wv[i].z + xv.w * wv[i].w;
    }
    acc += __shfl_xor(acc, 16);
    acc += __shfl_xor(acc, 32);
    if (l < 16) {
      if (o < 8) a_s[n * HEADS + o] = acc;
      else       a_n[n * HEADS + (o - 8)] = acc;
    }
    // conversion: q==0 lanes own chunk o (32B, L1-hot after the dot loads)
    if (q == 0) {
      const float4* xc = reinterpret_cast<const float4*>(x + (size_t)n * F_IN + o * 8);
      float4 y0 = xc[0], y1 = xc[1];
      uint4 pk;
      pk.x = cvt_pk_bf16(y0.x, y0.y);
      pk.y = cvt_pk_bf16(y0.z, y0.w);
      pk.z = cvt_pk_bf16(y1.x, y1.y);
      pk.w = cvt_pk_bf16(y1.z, y1.w);
      *reinterpret_cast<uint4*>(xb + (size_t)n * F_IN + o * 8) = pk;
    }
  }
}

// ---- 2) feat = xb @ Wt^T via MFMA (swapped operands, packed stores) ----
__global__ __launch_bounds__(256) void feat_gemm_mfma(
    const unsigned short* __restrict__ xb,   // [N][128] bf16
    const unsigned short* __restrict__ Wt,   // [256][128] bf16
    unsigned short* __restrict__ featb,      // [N][256] bf16
    int N) {
  const int t  = threadIdx.x;
  const int w  = t >> 6;        // wave 0..3
  const int l  = t & 63;
  const int lr = l & 15;        // node within 16-tile (D col)
  const int lq = l >> 4;        // k-slice / D row group
  const int n0 = blockIdx.x * 64 + w * 16;

  f32x4 acc[16];
#pragma unroll
  for (int ct = 0; ct < 16; ++ct) acc[ct] = (f32x4){0.f, 0.f, 0.f, 0.f};

  int ar = n0 + lr; if (ar >= N) ar = N - 1;
  const unsigned short* xrow = xb + (size_t)ar * F_IN + lq * 8;
  bf16x8 xfr[4];
#pragma unroll
  for (int kc = 0; kc < 4; ++kc)
    xfr[kc] = *reinterpret_cast<const bf16x8*>(xrow + kc * 32);

#pragma unroll
  for (int ct = 0; ct < 16; ++ct) {
    const unsigned short* wrow = Wt + (size_t)(ct * 16 + lr) * F_IN + lq * 8;
#pragma unroll
    for (int kc = 0; kc < 4; ++kc) {
      bf16x8 wfr = *reinterpret_cast<const bf16x8*>(wrow + kc * 32);
      acc[ct] = __builtin_amdgcn_mfma_f32_16x16x32_bf16(wfr, xfr[kc], acc[ct], 0, 0, 0);
    }
  }
  // lane owns node ar, cols ct*16 + lq*4 + r: packed dwordx2 stores
  if (n0 + lr < N) {
    unsigned short* frow = featb + (size_t)ar * F_ALL + lq * 4;
#pragma unroll
    for (int ct = 0; ct < 16; ++ct) {
      uint2 v;
      v.x = cvt_pk_bf16(acc[ct][0], acc[ct][1]);
      v.y = cvt_pk_bf16(acc[ct][2], acc[ct][3]);
      *reinterpret_cast<uint2*>(frow + ct * 16) = v;
    }
  }
}

// ---- 3) scatter: ONE wave/node; lane = (dp = l>>3, h = l&7).
// Pass A: one exp per (edge,head) (8 edges/group). Pass B: w via shfl,
// uint2 gather + 4 fma per edge per lane. Unified window loop for any deg. ----
__global__ __launch_bounds__(256) void gat_scatter(
    const unsigned short* __restrict__ featb,
    const float* __restrict__ a_s, const float* __restrict__ a_n,
    const int* __restrict__ col, const int* __restrict__ ptr,
    const float* __restrict__ biases, float* __restrict__ out, int N) {
  const int t  = threadIdx.x;
  const int n  = blockIdx.x * 4 + (t >> 6);   // 4 nodes per block, wave/node
  if (n >= N) return;
  const int l  = t & 63;
  const int h  = l & 7;                       // head
  const int dp = l >> 3;                      // dword-pair slot 0..7
  const int obase = h * F_OUT + dp * 4;       // 4 output features
  const size_t dbase = (size_t)h * 16 + dp * 2;

  const int start = ptr[n];
  const int deg   = ptr[n + 1] - start;

  const float4 bv = *reinterpret_cast<const float4*>(&biases[obase]);
  if (deg == 0) {
    *reinterpret_cast<float4*>(&out[(size_t)n * F_ALL + obase]) = bv;
    return;
  }

  const float as = a_s[n * HEADS + h];
  const unsigned* fu32 = reinterpret_cast<const unsigned*>(featb);

  float a0 = 0.f, a1 = 0.f, a2 = 0.f, a3 = 0.f, smp = 0.f;

  for (int cs = 0; cs < deg; cs += 32) {
    const int le = l & 31;
    int creg = (cs + le < deg) ? col[start + cs + le] : 0;
    const int wlim = deg - cs;                // edges remaining (>=1)
#pragma unroll
    for (int g = 0; g < 4; ++g) {
      // pass A: weight for (edge 8g+dp, head h) -- one exp per (edge,head)
      int ew = 8 * g + dp;
      int ce = __shfl(creg, ew, 32);
      float w = 0.f;
      if (ew < wlim) {
        float v = as + a_n[ce * HEADS + h];
        v = v > 0.f ? v : ALPHA * v;
        w = __expf(v);
      }
      smp += w;
      // pass B: distribute w, gather features
#pragma unroll
      for (int i = 0; i < 8; ++i) {
        int e = 8 * g + i;
        if (e >= wlim) break;                 // wave-uniform
        float wi = __shfl(w, 8 * i + h, 64);
        int   ci = __shfl(creg, e, 32);
        uint2 d  = *reinterpret_cast<const uint2*>(fu32 + (size_t)ci * 128 + dbase);
        a0 = fmaf(wi, bf16_lo(d.x), a0);
        a1 = fmaf(wi, bf16_hi(d.x), a1);
        a2 = fmaf(wi, bf16_lo(d.y), a2);
        a3 = fmaf(wi, bf16_hi(d.y), a3);
      }
      if (8 * g + 8 >= wlim) break;           // wave-uniform
    }
  }

  // reduce smp over the dp axis (lanes sharing h are stride-8 apart)
  smp += __shfl_xor(smp, 8);
  smp += __shfl_xor(smp, 16);
  smp += __shfl_xor(smp, 32);
  const float inv = 1.0f / smp;
  float4 o = {a0 * inv + bv.x, a1 * inv + bv.y, a2 * inv + bv.z, a3 * inv + bv.w};
  *reinterpret_cast<float4*>(&out[(size_t)n * F_ALL + obase]) = o;
}

extern "C" void kernel_launch(void* const* d_in, const int* in_sizes, int n_in,
                              void* d_out, int out_size, void* d_ws, size_t ws_size,
                              hipStream_t stream) {
  const float* x      = (const float*)d_in[0];
  const int*   row    = (const int*)d_in[1];
  const int*   col    = (const int*)d_in[2];
  const float* kern   = (const float*)d_in[3];
  const float* att_s  = (const float*)d_in[4];
  const float* att_n  = (const float*)d_in[5];
  const float* biases = (const float*)d_in[6];

  const int N = in_sizes[0] / F_IN;   // 100000
  const int E = in_sizes[1];          // 1600000

  // workspace: featb | xb | Wt | ws | wn | a_s | a_n | ptr   (~84 MB)
  unsigned short* featb = (unsigned short*)d_ws;
  unsigned short* xb    = featb + (size_t)N * F_ALL;
  unsigned short* Wt    = xb + (size_t)N * F_IN;
  float* ws  = (float*)(Wt + F_ALL * F_IN);
  float* wn  = ws + HEADS * F_IN;
  float* a_s = wn + HEADS * F_IN;
  float* a_n = a_s + (size_t)N * HEADS;
  int*   ptr = (int*)(a_n + (size_t)N * HEADS);
  float* out = (float*)d_out;

  hipLaunchKernelGGL(prep0, dim3((N + 1 + 255) / 256), dim3(256), 0, stream,
                     kern, att_s, att_n, row, Wt, ws, wn, ptr, N, E);
  hipLaunchKernelGGL(aproj_conv, dim3(2048), dim3(256), 0, stream,
                     x, ws, wn, xb, a_s, a_n, N);
  hipLaunchKernelGGL(feat_gemm_mfma, dim3((N + 63) / 64), dim3(256), 0, stream,
                     xb, Wt, featb, N);
  hipLaunchKernelGGL(gat_scatter, dim3((N + 3) / 4), dim3(256), 0, stream,
                     featb, a_s, a_n, col, ptr, biases, out, N);
}

// Round 13
// 260.755 us; speedup vs baseline: 1.1857x; 1.1857x over previous
//
#include <hip/hip_runtime.h>
#include <hip/hip_bf16.h>
#include <math.h>

// GAT forward: N=100000, E=1.6M (row sorted = dest), F_IN=128, F_OUT=32,
// HEADS=8, ALPHA=0.2. Output [N, 256] f32.
//
// Round 13 (compose proven pieces):
//  - scatter: R11 verbatim (150 us; best of 5 variants; ~structural gather
//    floor: 512 B/edge, 462 MB fetch @ ~3.8 TB/s).
//  - front-end: R6 verbatim (cheapest measured, ~103 us): prep does
//    x->bf16 + Wt + ws/wn + CSR ptr; gemm_aproj fuses MFMA GEMM and exact
//    f32 logits in one dispatch via block-range split.
//  - R12's exp-dedup re-lane reverted (VGPR 40 / occupancy 57% / +41 us).

#define F_IN   128
#define F_ALL  256   // HEADS * F_OUT
#define HEADS  8
#define F_OUT  32
#define ALPHA  0.2f

using f32x4  = __attribute__((ext_vector_type(4))) float;
using bf16x8 = __attribute__((ext_vector_type(8))) short;
using u16x8  = __attribute__((ext_vector_type(8))) unsigned short;

static __device__ __forceinline__ unsigned short f32_to_bf16(float f) {
  union { float f; unsigned u; } v; v.f = f;
  unsigned r = v.u + 0x7FFF + ((v.u >> 16) & 1);   // RNE
  return (unsigned short)(r >> 16);
}
static __device__ __forceinline__ unsigned cvt_pk_bf16(float lo, float hi) {
  unsigned r;
  asm("v_cvt_pk_bf16_f32 %0, %1, %2" : "=v"(r) : "v"(lo), "v"(hi));
  return r;
}
static __device__ __forceinline__ float bf16_lo(unsigned d) {
  return __uint_as_float(d << 16);
}
static __device__ __forceinline__ float bf16_hi(unsigned d) {
  return __uint_as_float(d & 0xffff0000u);
}

// ---- 0) prep: x->bf16, kern->Wt bf16, ws/wn = W@att (f32), CSR ptr ----
__global__ __launch_bounds__(256) void prep(const float* __restrict__ x,
                                            const float* __restrict__ kern,
                                            const float* __restrict__ att_s,
                                            const float* __restrict__ att_n,
                                            const int* __restrict__ row,
                                            unsigned short* __restrict__ xb,
                                            unsigned short* __restrict__ Wt,
                                            float* __restrict__ ws,
                                            float* __restrict__ wn,
                                            int* __restrict__ ptr,
                                            int total_x8, int N, int E) {
  int id = blockIdx.x * 256 + threadIdx.x;
  if (id < total_x8) {
    const float4* x4 = reinterpret_cast<const float4*>(x);
    float4 v0 = x4[(size_t)id * 2], v1 = x4[(size_t)id * 2 + 1];
    u16x8 o;
    o[0] = f32_to_bf16(v0.x); o[1] = f32_to_bf16(v0.y);
    o[2] = f32_to_bf16(v0.z); o[3] = f32_to_bf16(v0.w);
    o[4] = f32_to_bf16(v1.x); o[5] = f32_to_bf16(v1.y);
    o[6] = f32_to_bf16(v1.z); o[7] = f32_to_bf16(v1.w);
    *reinterpret_cast<u16x8*>(xb + (size_t)id * 8) = o;
  }
  if (id < F_ALL * F_IN) {          // Wt[c][k] = kern[c>>5][k][c&31]
    int c = id >> 7, k = id & 127;
    Wt[id] = f32_to_bf16(kern[(size_t)(c >> 5) * (F_IN * F_OUT) + k * F_OUT + (c & 31)]);
  }
  if (id < 2 * HEADS * F_IN) {      // ws[h][k], wn[h][k] (f32, exact)
    int which = id >> 10;
    int hk = id & 1023;
    int h = hk >> 7, k = hk & 127;
    const float* att = which ? att_n : att_s;
    float s = 0.f;
#pragma unroll
    for (int f = 0; f < F_OUT; ++f)
      s += kern[(size_t)h * (F_IN * F_OUT) + k * F_OUT + f] * att[h * F_OUT + f];
    (which ? wn : ws)[hk] = s;
  }
  if (id <= N) {                    // CSR offsets via binary search
    int lo = 0, hi = E;
    while (lo < hi) {
      int mid = (lo + hi) >> 1;
      if (row[mid] < id) lo = mid + 1; else hi = mid;
    }
    ptr[id] = lo;
  }
}

// ---- 1) fused: [0,GB): feat = xb@Wt^T via MFMA ; [GB,..): a_s/a_n = x@ws/wn ----
__global__ __launch_bounds__(256) void gemm_aproj(
    const unsigned short* __restrict__ xb,   // [N][128] bf16
    const unsigned short* __restrict__ Wt,   // [256][128] bf16
    const float* __restrict__ x,             // [N][128] f32
    const float* __restrict__ ws, const float* __restrict__ wn,
    unsigned short* __restrict__ featb,      // [N][256] bf16
    float* __restrict__ a_s, float* __restrict__ a_n,
    int N, int gemm_blocks, int aproj_waves) {
  const int t = threadIdx.x;

  if ((int)blockIdx.x < gemm_blocks) {
    // ---------- GEMM: D[wcol][node] = mfma(W, x) ----------
    const int w  = t >> 6;        // wave 0..3
    const int l  = t & 63;
    const int lr = l & 15;        // node within 16-tile (D col)
    const int lq = l >> 4;        // k-slice / D row group
    const int n0 = blockIdx.x * 64 + w * 16;

    f32x4 acc[16];
#pragma unroll
    for (int ct = 0; ct < 16; ++ct) acc[ct] = (f32x4){0.f, 0.f, 0.f, 0.f};

    int ar = n0 + lr; if (ar >= N) ar = N - 1;
    const unsigned short* xrow = xb + (size_t)ar * F_IN + lq * 8;
    bf16x8 xfr[4];
#pragma unroll
    for (int kc = 0; kc < 4; ++kc)
      xfr[kc] = *reinterpret_cast<const bf16x8*>(xrow + kc * 32);

#pragma unroll
    for (int ct = 0; ct < 16; ++ct) {
      const unsigned short* wrow = Wt + (size_t)(ct * 16 + lr) * F_IN + lq * 8;
#pragma unroll
      for (int kc = 0; kc < 4; ++kc) {
        bf16x8 wfr = *reinterpret_cast<const bf16x8*>(wrow + kc * 32);
        acc[ct] = __builtin_amdgcn_mfma_f32_16x16x32_bf16(wfr, xfr[kc], acc[ct], 0, 0, 0);
      }
    }
    // lane owns node ar, cols ct*16 + lq*4 + r: packed dwordx2 stores
    if (n0 + lr < N) {
      unsigned short* frow = featb + (size_t)ar * F_ALL + lq * 4;
#pragma unroll
      for (int ct = 0; ct < 16; ++ct) {
        uint2 v;
        v.x = cvt_pk_bf16(acc[ct][0], acc[ct][1]);
        v.y = cvt_pk_bf16(acc[ct][2], acc[ct][3]);
        *reinterpret_cast<uint2*>(frow + ct * 16) = v;
      }
    }
    return;
  }

  // ---------- a_proj: exact f32 logits, wave per node ----------
  const int l = t & 63;
  const int o = l & 15, q = l >> 4;
  const int wid = (((int)blockIdx.x - gemm_blocks) * 256 + t) >> 6;

  const float* wrow = (o < 8 ? ws + o * F_IN : wn + (o - 8) * F_IN) + q * 32;
  float4 wv[8];
#pragma unroll
  for (int i = 0; i < 8; i++) wv[i] = reinterpret_cast<const float4*>(wrow)[i];

  for (int n = wid; n < N; n += aproj_waves) {
    const float4* xr = reinterpret_cast<const float4*>(x + (size_t)n * F_IN + q * 32);
    float acc = 0.f;
#pragma unroll
    for (int i = 0; i < 8; i++) {
      float4 xv = xr[i];
      acc += xv.x * wv[i].x + xv.y * wv[i].y + xv.z * wv[i].z + xv.w * wv[i].w;
    }
    acc += __shfl_xor(acc, 16);
    acc += __shfl_xor(acc, 32);
    if (l < 16) {
      if (o < 8) a_s[n * HEADS + o] = acc;
      else       a_n[n * HEADS + (o - 8)] = acc;
    }
  }
}

// ---- 2) per-node softmax + SpMM: ONE wave per node, single fused pass ----
// 4 groups x 16 lanes; group j owns line j (heads 2j, 2j+1).
__global__ __launch_bounds__(256) void gat_scatter(
    const unsigned short* __restrict__ featb,
    const float* __restrict__ a_s, const float* __restrict__ a_n,
    const int* __restrict__ col, const int* __restrict__ ptr,
    const float* __restrict__ biases, float* __restrict__ out, int N) {
  const int t  = threadIdx.x;
  const int n  = blockIdx.x * 4 + (t >> 6);   // 4 nodes per block, wave/node
  if (n >= N) return;
  const int l  = t & 63;
  const int j  = l >> 4;                      // line group 0..3
  const int q  = l & 15;                      // lane within group
  const int h0 = 2 * j + (q >> 3);            // this lane's head
  const int obase = j * 64 + q * 4;           // 4 output features
  const size_t dbase = (size_t)j * 32 + q * 2; // dword offset in feat row

  const int start = ptr[n];
  const int deg   = ptr[n + 1] - start;

  const float4 bv = *reinterpret_cast<const float4*>(&biases[obase]);
  if (deg == 0) {
    *reinterpret_cast<float4*>(&out[(size_t)n * F_ALL + obase]) = bv;
    return;
  }

  const float as = a_s[n * HEADS + h0];
  const unsigned* fu32 = reinterpret_cast<const unsigned*>(featb);

  float a0 = 0.f, a1 = 0.f, a2 = 0.f, a3 = 0.f, sm = 0.f;

  if (deg <= 32) {
    // preload col into lanes 0..31 (lanes 32-63 mirror for width-32 shfl)
    const int le = l & 31;
    int creg = (le < deg) ? col[start + le] : 0;
#pragma unroll 4
    for (int e = 0; e < deg; ++e) {
      int c = __shfl(creg, e, 32);
      float an = a_n[c * HEADS + h0];
      float v = as + an;
      v = v > 0.f ? v : ALPHA * v;
      float w = __expf(v);
      sm += w;
      uint2 d = *reinterpret_cast<const uint2*>(fu32 + (size_t)c * 128 + dbase);
      a0 = fmaf(w, bf16_lo(d.x), a0);
      a1 = fmaf(w, bf16_hi(d.x), a1);
      a2 = fmaf(w, bf16_lo(d.y), a2);
      a3 = fmaf(w, bf16_hi(d.y), a3);
    }
  } else {
    // rare deg>32: same body, col loaded per edge (uniform broadcast)
    for (int e = 0; e < deg; ++e) {
      int c = col[start + e];
      float an = a_n[c * HEADS + h0];
      float v = as + an;
      v = v > 0.f ? v : ALPHA * v;
      float w = __expf(v);
      sm += w;
      uint2 d = *reinterpret_cast<const uint2*>(fu32 + (size_t)c * 128 + dbase);
      a0 = fmaf(w, bf16_lo(d.x), a0);
      a1 = fmaf(w, bf16_hi(d.x), a1);
      a2 = fmaf(w, bf16_lo(d.y), a2);
      a3 = fmaf(w, bf16_hi(d.y), a3);
    }
  }

  const float inv = 1.0f / sm;
  float4 o = {a0 * inv + bv.x, a1 * inv + bv.y, a2 * inv + bv.z, a3 * inv + bv.w};
  *reinterpret_cast<float4*>(&out[(size_t)n * F_ALL + obase]) = o;
}

extern "C" void kernel_launch(void* const* d_in, const int* in_sizes, int n_in,
                              void* d_out, int out_size, void* d_ws, size_t ws_size,
                              hipStream_t stream) {
  const float* x      = (const float*)d_in[0];
  const int*   row    = (const int*)d_in[1];
  const int*   col    = (const int*)d_in[2];
  const float* kern   = (const float*)d_in[3];
  const float* att_s  = (const float*)d_in[4];
  const float* att_n  = (const float*)d_in[5];
  const float* biases = (const float*)d_in[6];

  const int N = in_sizes[0] / F_IN;   // 100000
  const int E = in_sizes[1];          // 1600000

  // workspace: featb | xb | Wt | ws | wn | a_s | a_n | ptr   (~84 MB)
  unsigned short* featb = (unsigned short*)d_ws;
  unsigned short* xb    = featb + (size_t)N * F_ALL;
  unsigned short* Wt    = xb + (size_t)N * F_IN;
  float* ws  = (float*)(Wt + F_ALL * F_IN);
  float* wn  = ws + HEADS * F_IN;
  float* a_s = wn + HEADS * F_IN;
  float* a_n = a_s + (size_t)N * HEADS;
  int*   ptr = (int*)(a_n + (size_t)N * HEADS);
  float* out = (float*)d_out;

  const int total_x8     = N * F_IN / 8;   // 1.6M ids
  const int gemm_blocks  = (N + 63) / 64;
  const int aproj_blocks = 1024;
  const int aproj_waves  = aproj_blocks * 4;

  hipLaunchKernelGGL(prep, dim3((total_x8 + 255) / 256), dim3(256), 0, stream,
                     x, kern, att_s, att_n, row, xb, Wt, ws, wn, ptr, total_x8, N, E);
  hipLaunchKernelGGL(gemm_aproj, dim3(gemm_blocks + aproj_blocks), dim3(256), 0, stream,
                     xb, Wt, x, ws, wn, featb, a_s, a_n, N, gemm_blocks, aproj_waves);
  hipLaunchKernelGGL(gat_scatter, dim3((N + 3) / 4), dim3(256), 0, stream,
                     featb, a_s, a_n, col, ptr, biases, out, N);
}